// Round 2
// baseline (295.077 us; speedup 1.0000x reference)
//
#include <hip/hip_runtime.h>
#include <math.h>

#define Cc 96
#define Hh 128
#define Ww 128
#define HWsz (Hh*Ww)
#define TW 16
#define TH 8
#define LROW 18
#define LPLANE 180      // 10 rows * 18 cols per channel plane
#define CHUNK 24
#define NCHUNK 4

__device__ __forceinline__ void gload_lds4(const float* g, float* l) {
    __builtin_amdgcn_global_load_lds((const __attribute__((address_space(1))) void*)g,
                                     (__attribute__((address_space(3))) void*)l, 4, 0, 0);
}

__global__ __launch_bounds__(128, 2)
void alpf_fused(const float* __restrict__ x,
                const float* __restrict__ dw_w,
                const float* __restrict__ dw_b,
                const float* __restrict__ pw1_w,
                const float* __restrict__ pw1_b,
                const float* __restrict__ pw2_w,
                const float* __restrict__ pw2_b,
                float* __restrict__ out)
{
    __shared__ float lx[2][CHUNK * LPLANE];   // 2 x 17280 B = 34560 B

    const int tid = threadIdx.x;
    const int x0 = blockIdx.x * TW;
    const int y0 = blockIdx.y * TH;
    const int b  = blockIdx.z;
    const float* __restrict__ xb = x + (size_t)b * Cc * HWsz;

    // ---- halo geometry: each thread owns slot e1 (and e2 if e2<180) of a plane ----
    const int e1 = tid;                       // 0..127
    const int r1 = e1 / LROW, q1 = e1 - r1 * LROW;
    const int gy1 = y0 - 1 + r1, gx1 = x0 - 1 + q1;
    const bool ok1 = (gy1 >= 0) & (gy1 < Hh) & (gx1 >= 0) & (gx1 < Ww);
    const int g1 = gy1 * Ww + gx1;
    const int e2 = tid + 128;                 // 128..255
    const bool v2 = (e2 < LPLANE);            // tid < 52 (wave 0 only)
    const int r2 = e2 / LROW, q2 = e2 - r2 * LROW;
    const int gy2 = y0 - 1 + r2, gx2 = x0 - 1 + q2;
    const bool ok2 = v2 & (gy2 >= 0) & (gy2 < Hh) & (gx2 >= 0) & (gx2 < Ww);
    const int g2 = gy2 * Ww + gx2;
    const int wslot = tid & ~63;              // wave-uniform LDS slot base for e1 stripe
    const bool border = (x0 == 0) | (y0 == 0) | (x0 + TW == Ww) | (y0 + TH == Hh);

    // stage chunk [c0, c0+CHUNK) into lx[buf] (async; consumed after next barrier)
    auto stage = [&](int buf, int c0) {
        float* bp = &lx[buf][0];
        if (border) {
            #pragma unroll
            for (int p = 0; p < CHUNK; ++p) {
                if (!ok1)      bp[p * LPLANE + e1] = 0.f;
                if (v2 & !ok2) bp[p * LPLANE + e2] = 0.f;
            }
        }
        const float* xc0 = xb + (size_t)c0 * HWsz;
        #pragma unroll
        for (int p = 0; p < CHUNK; ++p) {
            const float* src = xc0 + p * HWsz;
            if (ok1) gload_lds4(src + g1, bp + p * LPLANE + wslot);
            if (ok2) gload_lds4(src + g2, bp + p * LPLANE + 128);
        }
    };

    // ---- per-pixel mapping ----
    const int lane = tid & 63;
    const int sx = lane & 15;                       // 0..15
    const int sy = (lane >> 4) + ((tid >> 6) << 2); // 0..7
    const int pbase = sy * LROW + sx;

    float t[48];
    #pragma unroll
    for (int o = 0; o < 48; ++o) t[o] = pw1_b[o];

    // ---- pass 1: depthwise 3x3 + pw1, channel-chunked, double-buffered ----
    stage(0, 0);
    __syncthreads();
    int cur = 0;
    for (int cc = 0; cc < NCHUNK; ++cc) {
        if (cc + 1 < NCHUNK) stage(cur ^ 1, (cc + 1) * CHUNK);
        const float* bp = &lx[cur][0];
        const int c0 = cc * CHUNK;
        #pragma unroll
        for (int p = 0; p < CHUNK; ++p) {
            const float* lp = bp + p * LPLANE + pbase;
            const int c = c0 + p;
            const float* wc = dw_w + c * 9;
            const float p0 = lp[0],        p1 = lp[1],        p2 = lp[2];
            const float p3 = lp[LROW],     p4 = lp[LROW+1],   p5 = lp[LROW+2];
            const float p6 = lp[2*LROW],   p7 = lp[2*LROW+1], p8 = lp[2*LROW+2];
            float a0 = fmaf(p0, wc[0], dw_b[c]);
            float a1 = p1 * wc[1];
            float a2 = p2 * wc[2];
            a0 = fmaf(p3, wc[3], a0);
            a1 = fmaf(p4, wc[4], a1);
            a2 = fmaf(p5, wc[5], a2);
            a0 = fmaf(p6, wc[6], a0);
            a1 = fmaf(p7, wc[7], a1);
            a2 = fmaf(p8, wc[8], a2);
            const float hc = a0 + a1 + a2;
            #pragma unroll
            for (int o = 0; o < 48; ++o)
                t[o] = fmaf(hc, pw1_w[o * Cc + c], t[o]);
        }
        __syncthreads();
        cur ^= 1;
    }

    // ---- pw2 (48->9) with fused LeakyReLU(0.2) ----
    float kw[9];
    #pragma unroll
    for (int k = 0; k < 9; ++k) kw[k] = pw2_b[k];
    #pragma unroll
    for (int o = 0; o < 48; ++o) {
        const float v = t[o];
        const float a = (v >= 0.f) ? v : 0.2f * v;
        #pragma unroll
        for (int k = 0; k < 9; ++k)
            kw[k] = fmaf(a, pw2_w[k * 48 + o], kw[k]);
    }

    // ---- softmax over 9 ----
    float m = kw[0];
    #pragma unroll
    for (int k = 1; k < 9; ++k) m = fmaxf(m, kw[k]);
    float s = 0.f;
    #pragma unroll
    for (int k = 0; k < 9; ++k) { kw[k] = __expf(kw[k] - m); s += kw[k]; }
    const float inv = 1.f / s;
    #pragma unroll
    for (int k = 0; k < 9; ++k) kw[k] *= inv;

    // ---- pass 2: smoothing, read x directly from global (L1/L2 hot) ----
    const int px_ = x0 + sx, py_ = y0 + sy;
    float* __restrict__ ob = out + (size_t)b * Cc * HWsz + (size_t)py_ * Ww + px_;
    const float* __restrict__ xp = xb + (size_t)py_ * Ww + px_;

    if (!border) {
        #pragma unroll 4
        for (int c = 0; c < Cc; ++c) {
            const float* xc = xp + (size_t)c * HWsz;
            float a0 = xc[-Ww-1] * kw[0];
            float a1 = xc[-Ww  ] * kw[1];
            float a2 = xc[-Ww+1] * kw[2];
            a0 = fmaf(xc[-1],   kw[3], a0);
            a1 = fmaf(xc[0],    kw[4], a1);
            a2 = fmaf(xc[1],    kw[5], a2);
            a0 = fmaf(xc[Ww-1], kw[6], a0);
            a1 = fmaf(xc[Ww],   kw[7], a1);
            a2 = fmaf(xc[Ww+1], kw[8], a2);
            ob[(size_t)c * HWsz] = a0 + a1 + a2;
        }
    } else {
        const bool okN = py_ > 0, okS = py_ < Hh - 1, okW = px_ > 0, okE = px_ < Ww - 1;
        const int  offs[9] = {-Ww-1, -Ww, -Ww+1, -1, 0, 1, Ww-1, Ww, Ww+1};
        const bool oky[9]  = {okN, okN, okN, true, true, true, okS, okS, okS};
        const bool okx[9]  = {okW, true, okE, okW, true, okE, okW, true, okE};
        int   idx[9];
        float kws[9];
        #pragma unroll
        for (int k = 0; k < 9; ++k) {
            const bool ok = oky[k] & okx[k];
            idx[k] = ok ? offs[k] : 0;       // safe address, value masked below
            kws[k] = ok ? kw[k] : 0.f;       // zero-padding folded into the tap
        }
        #pragma unroll 4
        for (int c = 0; c < Cc; ++c) {
            const float* xc = xp + (size_t)c * HWsz;
            float a0 = xc[idx[0]] * kws[0];
            float a1 = xc[idx[1]] * kws[1];
            float a2 = xc[idx[2]] * kws[2];
            a0 = fmaf(xc[idx[3]], kws[3], a0);
            a1 = fmaf(xc[idx[4]], kws[4], a1);
            a2 = fmaf(xc[idx[5]], kws[5], a2);
            a0 = fmaf(xc[idx[6]], kws[6], a0);
            a1 = fmaf(xc[idx[7]], kws[7], a1);
            a2 = fmaf(xc[idx[8]], kws[8], a2);
            ob[(size_t)c * HWsz] = a0 + a1 + a2;
        }
    }
}

extern "C" void kernel_launch(void* const* d_in, const int* in_sizes, int n_in,
                              void* d_out, int out_size, void* d_ws, size_t ws_size,
                              hipStream_t stream)
{
    const float* x     = (const float*)d_in[0];
    const float* dw_w  = (const float*)d_in[1];
    const float* dw_b  = (const float*)d_in[2];
    const float* pw1_w = (const float*)d_in[3];
    const float* pw1_b = (const float*)d_in[4];
    const float* pw2_w = (const float*)d_in[5];
    const float* pw2_b = (const float*)d_in[6];
    float* outp = (float*)d_out;

    const int B = in_sizes[0] / (Cc * HWsz);   // 8
    dim3 grid(Ww / TW, Hh / TH, B);
    alpf_fused<<<grid, 128, 0, stream>>>(x, dw_w, dw_b, pw1_w, pw1_b, pw2_w, pw2_b, outp);
}

// Round 3
// 146.404 us; speedup vs baseline: 2.0155x; 2.0155x over previous
//
#include <hip/hip_runtime.h>
#include <math.h>

#define Cc 96
#define Hh 128
#define Ww 128
#define HWsz (Hh*Ww)
#define TW 16
#define TH 8
#define LROW 18
#define LPLANE 180
#define CPAD 104   // ushort stride per position: 208B rows (16B-aligned), bank-spread

__device__ __forceinline__ unsigned f2bf(float f) {   // fp32 -> bf16 (RNE)
    unsigned u = __float_as_uint(f);
    return (u + 0x7fffu + ((u >> 16) & 1u)) >> 16;
}
__device__ __forceinline__ float bflo(unsigned w) { return __uint_as_float(w << 16); }
__device__ __forceinline__ float bfhi(unsigned w) { return __uint_as_float(w & 0xffff0000u); }

#define GETW(v, wi) ((wi)==0 ? (v).x : (wi)==1 ? (v).y : (wi)==2 ? (v).z : (v).w)

__global__ __launch_bounds__(128, 2)
void alpf_fused(const float* __restrict__ x,
                const float* __restrict__ dw_w,
                const float* __restrict__ dw_b,
                const float* __restrict__ pw1_w,
                const float* __restrict__ pw1_b,
                const float* __restrict__ pw2_w,
                const float* __restrict__ pw2_b,
                float* __restrict__ out)
{
    __shared__ unsigned short lx[LPLANE * CPAD];   // 37440 B -> 4 blocks/CU

    const int tid = threadIdx.x;
    const int x0 = blockIdx.x * TW;
    const int y0 = blockIdx.y * TH;
    const int b  = blockIdx.z;
    const float* __restrict__ xb = x + (size_t)b * Cc * HWsz;

    // ---- halo slot geometry: thread owns plane position e1 (and e2 if <180) ----
    const int e1 = tid;
    const int r1 = e1 / LROW, q1 = e1 - r1 * LROW;
    const int gy1 = y0 - 1 + r1, gx1 = x0 - 1 + q1;
    const bool ok1 = (gy1 >= 0) & (gy1 < Hh) & (gx1 >= 0) & (gx1 < Ww);
    const int g1 = gy1 * Ww + gx1;
    const int e2 = tid + 128;
    const bool v2 = (e2 < LPLANE);
    const int r2 = e2 / LROW, q2 = e2 - r2 * LROW;
    const int gy2 = y0 - 1 + r2, gx2 = x0 - 1 + q2;
    const bool ok2 = v2 & (gy2 >= 0) & (gy2 < Hh) & (gx2 >= 0) & (gx2 < Ww);
    const int g2 = gy2 * Ww + gx2;

    // ---- staging: x (f32, NCHW) -> LDS bf16, layout [pos][chan] ----
    #pragma unroll 2
    for (int cg = 0; cg < 12; ++cg) {
        const int c0 = cg * 8;
        const float* xc = xb + (size_t)c0 * HWsz;
        unsigned w0, w1, w2_, w3;
        {
            float v0 = ok1 ? xc[0*HWsz + g1] : 0.f;
            float v1 = ok1 ? xc[1*HWsz + g1] : 0.f;
            float v2_ = ok1 ? xc[2*HWsz + g1] : 0.f;
            float v3 = ok1 ? xc[3*HWsz + g1] : 0.f;
            float v4 = ok1 ? xc[4*HWsz + g1] : 0.f;
            float v5 = ok1 ? xc[5*HWsz + g1] : 0.f;
            float v6 = ok1 ? xc[6*HWsz + g1] : 0.f;
            float v7 = ok1 ? xc[7*HWsz + g1] : 0.f;
            w0 = f2bf(v0) | (f2bf(v1) << 16);
            w1 = f2bf(v2_) | (f2bf(v3) << 16);
            w2_ = f2bf(v4) | (f2bf(v5) << 16);
            w3 = f2bf(v6) | (f2bf(v7) << 16);
        }
        *reinterpret_cast<uint4*>(&lx[e1 * CPAD + c0]) = make_uint4(w0, w1, w2_, w3);
        if (v2) {
            float v0 = ok2 ? xc[0*HWsz + g2] : 0.f;
            float v1 = ok2 ? xc[1*HWsz + g2] : 0.f;
            float v2_ = ok2 ? xc[2*HWsz + g2] : 0.f;
            float v3 = ok2 ? xc[3*HWsz + g2] : 0.f;
            float v4 = ok2 ? xc[4*HWsz + g2] : 0.f;
            float v5 = ok2 ? xc[5*HWsz + g2] : 0.f;
            float v6 = ok2 ? xc[6*HWsz + g2] : 0.f;
            float v7 = ok2 ? xc[7*HWsz + g2] : 0.f;
            unsigned u0 = f2bf(v0) | (f2bf(v1) << 16);
            unsigned u1 = f2bf(v2_) | (f2bf(v3) << 16);
            unsigned u2 = f2bf(v4) | (f2bf(v5) << 16);
            unsigned u3 = f2bf(v6) | (f2bf(v7) << 16);
            *reinterpret_cast<uint4*>(&lx[e2 * CPAD + c0]) = make_uint4(u0, u1, u2, u3);
        }
    }
    __syncthreads();

    // ---- per-pixel mapping ----
    const int lane = tid & 63;
    const int sx = lane & 15;
    const int sy = (lane >> 4) + ((tid >> 6) << 2);
    const unsigned short* lb = &lx[(sy * LROW + sx) * CPAD];

    float t[48];
    #pragma unroll
    for (int o = 0; o < 48; ++o) t[o] = pw1_b[o];

    // ---- pass 1: depthwise 3x3 + pw1 accumulate, 8 channels per group ----
    #pragma unroll 2
    for (int cg = 0; cg < 12; ++cg) {
        const int c0 = cg * 8;
        uint4 tp[9];
        #pragma unroll
        for (int dy = 0; dy < 3; ++dy)
            #pragma unroll
            for (int dx = 0; dx < 3; ++dx)
                tp[dy*3+dx] = *reinterpret_cast<const uint4*>(&lb[(dy*LROW+dx)*CPAD + c0]);

        float hc[8];
        #pragma unroll
        for (int j = 0; j < 8; ++j) {
            const int wi = j >> 1;
            const float* wc = dw_w + (size_t)(c0 + j) * 9;
            #define EXTJ(k) ((j & 1) ? bfhi(GETW(tp[k], wi)) : bflo(GETW(tp[k], wi)))
            float a0 = fmaf(EXTJ(0), wc[0], dw_b[c0 + j]);
            float a1 = EXTJ(1) * wc[1];
            float a2 = EXTJ(2) * wc[2];
            a0 = fmaf(EXTJ(3), wc[3], a0);
            a1 = fmaf(EXTJ(4), wc[4], a1);
            a2 = fmaf(EXTJ(5), wc[5], a2);
            a0 = fmaf(EXTJ(6), wc[6], a0);
            a1 = fmaf(EXTJ(7), wc[7], a1);
            a2 = fmaf(EXTJ(8), wc[8], a2);
            hc[j] = a0 + a1 + a2;
            #undef EXTJ
        }
        #pragma unroll
        for (int o = 0; o < 48; ++o) {
            const float* wr = pw1_w + o * Cc + c0;   // 8 contiguous words -> s_load_x8
            float s = t[o];
            s = fmaf(hc[0], wr[0], s);
            s = fmaf(hc[1], wr[1], s);
            s = fmaf(hc[2], wr[2], s);
            s = fmaf(hc[3], wr[3], s);
            s = fmaf(hc[4], wr[4], s);
            s = fmaf(hc[5], wr[5], s);
            s = fmaf(hc[6], wr[6], s);
            s = fmaf(hc[7], wr[7], s);
            t[o] = s;
        }
    }

    // ---- LeakyReLU + pw2 (48->9), contiguous scalar weights per k ----
    #pragma unroll
    for (int o = 0; o < 48; ++o) { float v = t[o]; t[o] = (v >= 0.f) ? v : 0.2f * v; }
    float kw[9];
    #pragma unroll
    for (int k = 0; k < 9; ++k) {
        const float* w2 = pw2_w + k * 48;
        float s = pw2_b[k];
        #pragma unroll
        for (int o = 0; o < 48; ++o) s = fmaf(t[o], w2[o], s);
        kw[k] = s;
    }

    // ---- softmax over 9 ----
    float m = kw[0];
    #pragma unroll
    for (int k = 1; k < 9; ++k) m = fmaxf(m, kw[k]);
    float s = 0.f;
    #pragma unroll
    for (int k = 0; k < 9; ++k) { kw[k] = __expf(kw[k] - m); s += kw[k]; }
    const float inv = 1.f / s;
    #pragma unroll
    for (int k = 0; k < 9; ++k) kw[k] *= inv;

    // ---- pass 2: smoothing from the same resident LDS tile ----
    float* __restrict__ ob = out + (size_t)b * Cc * HWsz + (size_t)(y0 + sy) * Ww + (x0 + sx);
    #pragma unroll 2
    for (int cg = 0; cg < 12; ++cg) {
        const int c0 = cg * 8;
        uint4 tp[9];
        #pragma unroll
        for (int dy = 0; dy < 3; ++dy)
            #pragma unroll
            for (int dx = 0; dx < 3; ++dx)
                tp[dy*3+dx] = *reinterpret_cast<const uint4*>(&lb[(dy*LROW+dx)*CPAD + c0]);
        #pragma unroll
        for (int j = 0; j < 8; ++j) {
            const int wi = j >> 1;
            #define EXTJ(k) ((j & 1) ? bfhi(GETW(tp[k], wi)) : bflo(GETW(tp[k], wi)))
            float a0 = EXTJ(0) * kw[0];
            float a1 = EXTJ(1) * kw[1];
            float a2 = EXTJ(2) * kw[2];
            a0 = fmaf(EXTJ(3), kw[3], a0);
            a1 = fmaf(EXTJ(4), kw[4], a1);
            a2 = fmaf(EXTJ(5), kw[5], a2);
            a0 = fmaf(EXTJ(6), kw[6], a0);
            a1 = fmaf(EXTJ(7), kw[7], a1);
            a2 = fmaf(EXTJ(8), kw[8], a2);
            ob[(size_t)(c0 + j) * HWsz] = a0 + a1 + a2;
            #undef EXTJ
        }
    }
}

extern "C" void kernel_launch(void* const* d_in, const int* in_sizes, int n_in,
                              void* d_out, int out_size, void* d_ws, size_t ws_size,
                              hipStream_t stream)
{
    const float* x     = (const float*)d_in[0];
    const float* dw_w  = (const float*)d_in[1];
    const float* dw_b  = (const float*)d_in[2];
    const float* pw1_w = (const float*)d_in[3];
    const float* pw1_b = (const float*)d_in[4];
    const float* pw2_w = (const float*)d_in[5];
    const float* pw2_b = (const float*)d_in[6];
    float* outp = (float*)d_out;

    const int B = in_sizes[0] / (Cc * HWsz);   // 8
    dim3 grid(Ww / TW, Hh / TH, B);
    alpf_fused<<<grid, 128, 0, stream>>>(x, dw_w, dw_b, pw1_w, pw1_b, pw2_w, pw2_b, outp);
}

// Round 5
// 72.411 us; speedup vs baseline: 4.0750x; 2.0218x over previous
//
#include <hip/hip_runtime.h>
#include <math.h>

#define Cc 96
#define Hh 128
#define Ww 128
#define HWsz (Hh*Ww)
#define TW 16
#define TH 8
#define LROW 18
#define LPLANE 180
#define CPAD 104      // ushort stride per position: 208B rows, 16B-aligned

typedef _Float16 h2 __attribute__((ext_vector_type(2)));

__device__ __forceinline__ unsigned pkrtz_u(float a, float b) {
    return __builtin_bit_cast(unsigned, __builtin_amdgcn_cvt_pkrtz(a, b));
}
__device__ __forceinline__ h2 pk2(float a, float b) {
    return __builtin_bit_cast(h2, __builtin_amdgcn_cvt_pkrtz(a, b));
}
__device__ __forceinline__ h2 u2h(unsigned u) { return __builtin_bit_cast(h2, u); }

#define GETW(v, wi) ((wi)==0 ? (v).x : (wi)==1 ? (v).y : (wi)==2 ? (v).z : (v).w)

// packed-weight layout in d_ws (dword offsets)
#define OFF_DWB  0       // [48]       (dw_b[2p], dw_b[2p+1])
#define OFF_DWW  48      // [48][9]    (dw_w[2p][k], dw_w[2p+1][k])
#define OFF_PW1  480     // [48][48]   [pair p][o]: (pw1_w[o][2p], pw1_w[o][2p+1])
#define OFF_PW2  2784    // [9][24]    [k][tp]: (pw2_w[k][2tp], pw2_w[k][2tp+1])
#define NPK      3000

__global__ void alpf_prep(const float* __restrict__ dw_w, const float* __restrict__ dw_b,
                          const float* __restrict__ pw1_w, const float* __restrict__ pw2_w,
                          unsigned* __restrict__ wpk)
{
    int i = blockIdx.x * 256 + threadIdx.x;
    if (i >= NPK) return;
    unsigned v;
    if (i < OFF_DWW) {
        int p = i;
        v = pkrtz_u(dw_b[2*p], dw_b[2*p+1]);
    } else if (i < OFF_PW1) {
        int idx = i - OFF_DWW; int p = idx / 9, k = idx - 9*p;
        v = pkrtz_u(dw_w[(2*p)*9 + k], dw_w[(2*p+1)*9 + k]);
    } else if (i < OFF_PW2) {
        int idx = i - OFF_PW1; int p = idx / 48, o = idx - 48*p;
        v = pkrtz_u(pw1_w[o*Cc + 2*p], pw1_w[o*Cc + 2*p+1]);
    } else {
        int idx = i - OFF_PW2; int k = idx / 24, p = idx - 24*k;
        v = pkrtz_u(pw2_w[k*48 + 2*p], pw2_w[k*48 + 2*p+1]);
    }
    wpk[i] = v;
}

__global__ __launch_bounds__(128, 2)
void alpf_fused(const float* __restrict__ x,
                const float* __restrict__ pw1_b,
                const float* __restrict__ pw2_b,
                const unsigned* __restrict__ wpk,
                float* __restrict__ out)
{
    __shared__ unsigned short lx[LPLANE * CPAD];   // 37440 B -> 4 blocks/CU

    const int tid = threadIdx.x;
    const int x0 = blockIdx.x * TW;
    const int y0 = blockIdx.y * TH;
    const int b  = blockIdx.z;
    const float* __restrict__ xb = x + (size_t)b * Cc * HWsz;

    // ---- halo slot geometry ----
    const int e1 = tid;
    const int r1 = e1 / LROW, q1 = e1 - r1 * LROW;
    const int gy1 = y0 - 1 + r1, gx1 = x0 - 1 + q1;
    const bool ok1 = (gy1 >= 0) & (gy1 < Hh) & (gx1 >= 0) & (gx1 < Ww);
    const int g1 = gy1 * Ww + gx1;
    const int e2 = tid + 128;
    const bool v2 = (e2 < LPLANE);
    const int r2 = e2 / LROW, q2 = e2 - r2 * LROW;
    const int gy2 = y0 - 1 + r2, gx2 = x0 - 1 + q2;
    const bool ok2 = v2 & (gy2 >= 0) & (gy2 < Hh) & (gx2 >= 0) & (gx2 < Ww);
    const int g2 = gy2 * Ww + gx2;

    // ---- staging: f32 global -> fp16 LDS, layout [pos][chan] ----
    #pragma unroll 2
    for (int cg = 0; cg < 12; ++cg) {
        const int c0 = cg * 8;
        const float* xc = xb + (size_t)c0 * HWsz;
        {
            float v0 = ok1 ? xc[0*HWsz + g1] : 0.f;
            float v1 = ok1 ? xc[1*HWsz + g1] : 0.f;
            float v2_ = ok1 ? xc[2*HWsz + g1] : 0.f;
            float v3 = ok1 ? xc[3*HWsz + g1] : 0.f;
            float v4 = ok1 ? xc[4*HWsz + g1] : 0.f;
            float v5 = ok1 ? xc[5*HWsz + g1] : 0.f;
            float v6 = ok1 ? xc[6*HWsz + g1] : 0.f;
            float v7 = ok1 ? xc[7*HWsz + g1] : 0.f;
            *reinterpret_cast<uint4*>(&lx[e1 * CPAD + c0]) =
                make_uint4(pkrtz_u(v0,v1), pkrtz_u(v2_,v3), pkrtz_u(v4,v5), pkrtz_u(v6,v7));
        }
        if (v2) {
            float v0 = ok2 ? xc[0*HWsz + g2] : 0.f;
            float v1 = ok2 ? xc[1*HWsz + g2] : 0.f;
            float v2_ = ok2 ? xc[2*HWsz + g2] : 0.f;
            float v3 = ok2 ? xc[3*HWsz + g2] : 0.f;
            float v4 = ok2 ? xc[4*HWsz + g2] : 0.f;
            float v5 = ok2 ? xc[5*HWsz + g2] : 0.f;
            float v6 = ok2 ? xc[6*HWsz + g2] : 0.f;
            float v7 = ok2 ? xc[7*HWsz + g2] : 0.f;
            *reinterpret_cast<uint4*>(&lx[e2 * CPAD + c0]) =
                make_uint4(pkrtz_u(v0,v1), pkrtz_u(v2_,v3), pkrtz_u(v4,v5), pkrtz_u(v6,v7));
        }
    }
    __syncthreads();

    // ---- per-pixel mapping ----
    const int lane = tid & 63;
    const int sx = lane & 15;
    const int sy = (lane >> 4) + ((tid >> 6) << 2);
    const unsigned short* lb = &lx[(sy * LROW + sx) * CPAD];

    float t[48];
    #pragma unroll
    for (int o = 0; o < 48; ++o) t[o] = pw1_b[o];

    // ---- pass 1: depthwise 3x3 (packed fp16) + pw1 (dot2), 8 ch / group ----
    #pragma unroll 2
    for (int cg = 0; cg < 12; ++cg) {
        const int c0 = cg * 8;
        uint4 tp[9];
        #pragma unroll
        for (int k = 0; k < 9; ++k) {
            const int dy = k / 3, dx = k - 3 * dy;
            tp[k] = *reinterpret_cast<const uint4*>(&lb[(dy*LROW+dx)*CPAD + c0]);
        }
        h2 hc[4];
        #pragma unroll
        for (int l = 0; l < 4; ++l) {
            h2 acc = u2h(wpk[OFF_DWB + cg*4 + l]);             // bias pair
            #pragma unroll
            for (int k = 0; k < 9; ++k)
                acc = __builtin_elementwise_fma(u2h(GETW(tp[k], l)),
                                                u2h(wpk[OFF_DWW + (cg*4+l)*9 + k]), acc);
            hc[l] = acc;
        }
        #pragma unroll
        for (int o = 0; o < 48; ++o) {
            float s = t[o];
            s = __builtin_amdgcn_fdot2(hc[0], u2h(wpk[OFF_PW1 + (cg*4+0)*48 + o]), s, false);
            s = __builtin_amdgcn_fdot2(hc[1], u2h(wpk[OFF_PW1 + (cg*4+1)*48 + o]), s, false);
            s = __builtin_amdgcn_fdot2(hc[2], u2h(wpk[OFF_PW1 + (cg*4+2)*48 + o]), s, false);
            s = __builtin_amdgcn_fdot2(hc[3], u2h(wpk[OFF_PW1 + (cg*4+3)*48 + o]), s, false);
            t[o] = s;
        }
    }

    // ---- LeakyReLU + pack t -> fp16 pairs + pw2 (dot2) ----
    #pragma unroll
    for (int o = 0; o < 48; ++o) { float v = t[o]; t[o] = (v >= 0.f) ? v : 0.2f * v; }
    h2 tp2[24];
    #pragma unroll
    for (int p = 0; p < 24; ++p)
        tp2[p] = pk2(t[2*p], t[2*p+1]);
    float kw[9];
    #pragma unroll
    for (int k = 0; k < 9; ++k) {
        float s = pw2_b[k];
        #pragma unroll
        for (int p = 0; p < 24; ++p)
            s = __builtin_amdgcn_fdot2(tp2[p], u2h(wpk[OFF_PW2 + k*24 + p]), s, false);
        kw[k] = s;
    }

    // ---- softmax over 9 ----
    float m = kw[0];
    #pragma unroll
    for (int k = 1; k < 9; ++k) m = fmaxf(m, kw[k]);
    float s = 0.f;
    #pragma unroll
    for (int k = 0; k < 9; ++k) { kw[k] = __expf(kw[k] - m); s += kw[k]; }
    const float inv = 1.f / s;
    h2 kwp[9];
    #pragma unroll
    for (int k = 0; k < 9; ++k) { kw[k] *= inv; kwp[k] = pk2(kw[k], kw[k]); }

    // ---- pass 2: smoothing (packed fp16, 3 short accumulator chains) ----
    float* __restrict__ ob = out + (size_t)b * Cc * HWsz + (size_t)(y0 + sy) * Ww + (x0 + sx);
    #pragma unroll 2
    for (int cg = 0; cg < 12; ++cg) {
        const int c0 = cg * 8;
        uint4 tp[9];
        #pragma unroll
        for (int k = 0; k < 9; ++k) {
            const int dy = k / 3, dx = k - 3 * dy;
            tp[k] = *reinterpret_cast<const uint4*>(&lb[(dy*LROW+dx)*CPAD + c0]);
        }
        #pragma unroll
        for (int l = 0; l < 4; ++l) {
            h2 a0 = u2h(GETW(tp[0], l)) * kwp[0];
            h2 a1 = u2h(GETW(tp[1], l)) * kwp[1];
            h2 a2 = u2h(GETW(tp[2], l)) * kwp[2];
            a0 = __builtin_elementwise_fma(u2h(GETW(tp[3], l)), kwp[3], a0);
            a1 = __builtin_elementwise_fma(u2h(GETW(tp[4], l)), kwp[4], a1);
            a2 = __builtin_elementwise_fma(u2h(GETW(tp[5], l)), kwp[5], a2);
            a0 = __builtin_elementwise_fma(u2h(GETW(tp[6], l)), kwp[6], a0);
            a1 = __builtin_elementwise_fma(u2h(GETW(tp[7], l)), kwp[7], a1);
            a2 = __builtin_elementwise_fma(u2h(GETW(tp[8], l)), kwp[8], a2);
            float olo = (float)a0.x + (float)a1.x + (float)a2.x;
            float ohi = (float)a0.y + (float)a1.y + (float)a2.y;
            ob[(size_t)(c0 + 2*l)     * HWsz] = olo;
            ob[(size_t)(c0 + 2*l + 1) * HWsz] = ohi;
        }
    }
}

extern "C" void kernel_launch(void* const* d_in, const int* in_sizes, int n_in,
                              void* d_out, int out_size, void* d_ws, size_t ws_size,
                              hipStream_t stream)
{
    const float* x     = (const float*)d_in[0];
    const float* dw_w  = (const float*)d_in[1];
    const float* dw_b  = (const float*)d_in[2];
    const float* pw1_w = (const float*)d_in[3];
    const float* pw1_b = (const float*)d_in[4];
    const float* pw2_w = (const float*)d_in[5];
    const float* pw2_b = (const float*)d_in[6];
    float* outp = (float*)d_out;
    unsigned* wpk = (unsigned*)d_ws;

    alpf_prep<<<(NPK + 255) / 256, 256, 0, stream>>>(dw_w, dw_b, pw1_w, pw2_w, wpk);

    const int B = in_sizes[0] / (Cc * HWsz);   // 8
    dim3 grid(Ww / TW, Hh / TH, B);
    alpf_fused<<<grid, 128, 0, stream>>>(x, pw1_b, pw2_b, wpk, outp);
}